// Round 2
// baseline (2003.480 us; speedup 1.0000x reference)
//
#include <hip/hip_runtime.h>
#include <stdint.h>

// Problem constants (fixed by setup_inputs)
#define BATCH 2
#define NH    16
#define NKV   4
#define SEQ   2048
#define HD    128
#define WIN   512
// G = NH/NKV = 4, scale = 1/sqrt(128)

// One wave (64 lanes) per query row; inputs/outputs are FLOAT32 per the
// reference (round-1 NaN diagnosed as bf16 misread of f32 buffers).
// Lane owns dims [2*lane, 2*lane+1] as a float2. Per key: coalesced 8B/lane
// K and V loads, 2 FMAs, 6-step butterfly reduce, online-softmax update.
__global__ __launch_bounds__(256) void fa_wave_per_query_f32(
    const float2* __restrict__ qg,   // [B,H,S,D/2]
    const float2* __restrict__ kg,   // [B,HKV,S,D/2]
    const float2* __restrict__ vg,   // [B,HKV,S,D/2]
    float2* __restrict__ outg)       // [B,H,S,D/2]
{
    const int lane = threadIdx.x & 63;
    const int wave = threadIdx.x >> 6;
    const int qi   = blockIdx.x * 4 + wave;      // global query id over B*H*S
    const int i    = qi & (SEQ - 1);
    const int bh   = qi >> 11;                   // b*NH + h  (SEQ = 2^11)
    const int h    = bh & (NH - 1);
    const int b    = bh >> 4;                    // NH = 16
    const int hkv  = h >> 2;                     // G = 4

    const size_t qoff   = ((size_t)bh * SEQ + (size_t)i) * (HD / 2);
    const size_t kvbase = ((size_t)(b * NKV + hkv) * SEQ) * (HD / 2);

    const float scale = 0.08838834764831845f;    // 1/sqrt(128)
    const float2 qp = qg[qoff + lane];
    const float q0 = qp.x * scale;
    const float q1 = qp.y * scale;

    float m = -1e30f, l = 0.0f, o0 = 0.0f, o1 = 0.0f;

    int j0 = i - (WIN - 1);
    if (j0 < 0) j0 = 0;

    for (int j = j0; j <= i; ++j) {
        const size_t roff = kvbase + (size_t)j * (HD / 2) + lane;
        const float2 kp = kg[roff];
        const float2 vp = vg[roff];

        float s = q0 * kp.x + q1 * kp.y;
        #pragma unroll
        for (int off = 32; off > 0; off >>= 1)
            s += __shfl_xor(s, off, 64);

        const float mn    = fmaxf(m, s);
        const float alpha = __expf(m - mn);
        const float p     = __expf(s - mn);

        l  = l  * alpha + p;
        o0 = o0 * alpha + p * vp.x;
        o1 = o1 * alpha + p * vp.y;
        m  = mn;
    }

    const float inv = 1.0f / l;
    outg[qoff + lane] = make_float2(o0 * inv, o1 * inv);
}

extern "C" void kernel_launch(void* const* d_in, const int* in_sizes, int n_in,
                              void* d_out, int out_size, void* d_ws, size_t ws_size,
                              hipStream_t stream) {
    const float2* q = (const float2*)d_in[0];
    const float2* k = (const float2*)d_in[1];
    const float2* v = (const float2*)d_in[2];
    float2* out     = (float2*)d_out;

    const int total_queries = BATCH * NH * SEQ;      // 65536
    dim3 grid(total_queries / 4);                    // 4 waves per block
    dim3 block(256);
    hipLaunchKernelGGL(fa_wave_per_query_f32, grid, block, 0, stream, q, k, v, out);
}

// Round 4
// 181.481 us; speedup vs baseline: 11.0396x; 11.0396x over previous
//
#include <hip/hip_runtime.h>
#include <hip/hip_bf16.h>
#include <stdint.h>

#define SEQ 2048
#define HD  128
#define WIN 512
#define NH  16
#define NKV 4
#define BATCH 2

typedef __attribute__((ext_vector_type(8))) short bf16x8;
typedef __attribute__((ext_vector_type(4))) float f32x4;

// LDS row strides in bf16 elements (all byte-strides multiples of 16B for b128)
#define KSTR 136   // K tile  [64 keys][128 dims]
#define VSTR 72    // V^T tile [128 dims][64 keys]
#define PSTR 72    // P tile per wave [32 q][64 keys]

__device__ __forceinline__ uint32_t pk2(float a, float b) {
    __hip_bfloat162 h = __float22bfloat162_rn(make_float2(a, b));
    return *reinterpret_cast<uint32_t*>(&h);
}
__device__ __forceinline__ uint16_t pk1(float a) {
    __hip_bfloat16 h = __float2bfloat16(a);
    return *reinterpret_cast<uint16_t*>(&h);
}

// Block: 256 threads = 4 waves; each wave owns 32 queries; block owns 128.
// S^T = K·Q^T (keys=rows, queries=cols) so softmax stats are per-column
// (q = lane&15): 2-shfl reductions, 2 regs for m/l. P round-trips LDS
// row-major [q][key]; V staged transposed so PV B-frags are b128.
__global__ __launch_bounds__(256, 2) void fa_mfma(
    const float* __restrict__ q,
    const float* __restrict__ k,
    const float* __restrict__ v,
    float* __restrict__ out)
{
    const int tid  = threadIdx.x;
    const int wave = tid >> 6;
    const int lane = tid & 63;
    const int l4   = lane >> 4;
    const int l15  = lane & 15;

    const int bh   = blockIdx.x >> 4;      // b*NH + h
    const int qblk = blockIdx.x & 15;
    const int q0   = qblk << 7;            // 128 queries per block
    const int hkv  = (bh & (NH - 1)) >> 2; // G = 4
    const int b    = bh >> 4;

    const int i0   = q0 + wave * 32;       // wave's first query row

    __shared__ __align__(16) uint16_t lds_k[64 * KSTR];
    __shared__ __align__(16) uint16_t lds_vt[HD * VSTR];
    __shared__ __align__(16) uint16_t lds_p[4 * 32 * PSTR];
    uint16_t* pw = &lds_p[wave * 32 * PSTR];

    const float scale = 0.08838834764831845f;  // 1/sqrt(128)

    const size_t qbase  = (size_t)bh * SEQ * HD;
    const size_t kvbase = (size_t)(b * NKV + hkv) * SEQ * HD;

    // ---- preload Q fragments (B-operand: B[k=dim][n=q]) ----
    union { bf16x8 f; uint32_t u[4]; } qf[2][4];
    #pragma unroll
    for (int nt = 0; nt < 2; ++nt) {
        const float* qr = q + qbase + (size_t)(i0 + nt * 16 + l15) * HD;
        #pragma unroll
        for (int ks = 0; ks < 4; ++ks) {
            const float4* g = reinterpret_cast<const float4*>(qr + ks * 32 + l4 * 8);
            float4 a = g[0], bq = g[1];
            qf[nt][ks].u[0] = pk2(a.x * scale, a.y * scale);
            qf[nt][ks].u[1] = pk2(a.z * scale, a.w * scale);
            qf[nt][ks].u[2] = pk2(bq.x * scale, bq.y * scale);
            qf[nt][ks].u[3] = pk2(bq.z * scale, bq.w * scale);
        }
    }

    f32x4 O[2][8];
    #pragma unroll
    for (int a1 = 0; a1 < 2; ++a1)
        #pragma unroll
        for (int a2 = 0; a2 < 8; ++a2) O[a1][a2] = (f32x4){0.f, 0.f, 0.f, 0.f};
    float mrow[2] = {-1e30f, -1e30f};
    float lrow[2] = {0.f, 0.f};

    const int kt_lo_blk = (q0 >= 512) ? ((q0 - 511) >> 6) : 0;
    const int kt_hi_blk = (q0 + 127) >> 6;
    const int lo_w = (i0 >= 512) ? ((i0 - 511) >> 6) : 0;
    const int hi_w = (i0 + 31) >> 6;

    for (int kt = kt_lo_blk; kt <= kt_hi_blk; ++kt) {
        // ---------- stage K tile: row-major bf16, b128 writes ----------
        const float* kp = k + kvbase + (size_t)kt * 64 * HD;
        #pragma unroll
        for (int it = 0; it < 4; ++it) {
            int flat8 = tid + it * 256;   // 1024 8-elem chunks
            int key   = flat8 >> 4;
            int ch    = flat8 & 15;
            const float4* g = reinterpret_cast<const float4*>(kp + key * HD + ch * 8);
            float4 a = g[0], bq = g[1];
            uint4 wv;
            wv.x = pk2(a.x, a.y);  wv.y = pk2(a.z, a.w);
            wv.z = pk2(bq.x, bq.y); wv.w = pk2(bq.z, bq.w);
            *reinterpret_cast<uint4*>(&lds_k[key * KSTR + ch * 8]) = wv;
        }
        // ---------- stage V^T: lane-paired u16 writes (same-dword merge) ----
        const float* vp = v + kvbase + (size_t)kt * 64 * HD;
        {
            int kk = 2 * (lane >> 5) + (lane & 1);   // key offset in 4-key group
            int p  = (lane >> 1) & 15;               // dim offset in 16-dim group
            #pragma unroll
            for (int it = 0; it < 32; ++it) {
                int kgl = it >> 3, dg = it & 7;
                int key = wave * 16 + kgl * 4 + kk;
                int dim = dg * 16 + p;
                lds_vt[dim * VSTR + key] = pk1(vp[key * HD + dim]);
            }
        }
        __syncthreads();

        if (kt >= lo_w && kt <= hi_w) {
            // ---------- S^T = K · Q^T ----------
            f32x4 sf[4][2];
            #pragma unroll
            for (int mt = 0; mt < 4; ++mt) {
                #pragma unroll
                for (int nt = 0; nt < 2; ++nt) sf[mt][nt] = (f32x4){0.f, 0.f, 0.f, 0.f};
                #pragma unroll
                for (int ks = 0; ks < 4; ++ks) {
                    bf16x8 af = *reinterpret_cast<const bf16x8*>(
                        &lds_k[(mt * 16 + l15) * KSTR + ks * 32 + l4 * 8]);
                    #pragma unroll
                    for (int nt = 0; nt < 2; ++nt)
                        sf[mt][nt] = __builtin_amdgcn_mfma_f32_16x16x32_bf16(
                            af, qf[nt][ks].f, sf[mt][nt], 0, 0, 0);
                }
            }
            // ---------- mask (first/window and last/causal tiles only) ------
            const bool needmask = (kt == hi_w) || (kt == lo_w && i0 > 511);
            if (needmask) {
                #pragma unroll
                for (int mt = 0; mt < 4; ++mt) {
                    int jb = kt * 64 + mt * 16 + l4 * 4;
                    #pragma unroll
                    for (int nt = 0; nt < 2; ++nt) {
                        int iq = i0 + nt * 16 + l15;
                        #pragma unroll
                        for (int r = 0; r < 4; ++r) {
                            int j = jb + r;
                            if (!((j <= iq) && (iq - j < WIN))) sf[mt][nt][r] = -1e30f;
                        }
                    }
                }
            }
            // ---------- online softmax (per-column stats) ----------
            float alpha[2];
            #pragma unroll
            for (int nt = 0; nt < 2; ++nt) {
                float tm = -1e30f;
                #pragma unroll
                for (int mt = 0; mt < 4; ++mt)
                    #pragma unroll
                    for (int r = 0; r < 4; ++r) tm = fmaxf(tm, sf[mt][nt][r]);
                tm = fmaxf(tm, __shfl_xor(tm, 16, 64));
                tm = fmaxf(tm, __shfl_xor(tm, 32, 64));
                float mn = fmaxf(mrow[nt], tm);
                alpha[nt] = __expf(mrow[nt] - mn);
                mrow[nt] = mn;
                float me = fmaxf(mn, -1e20f);   // fully-masked rows -> p = 0
                float ts = 0.f;
                #pragma unroll
                for (int mt = 0; mt < 4; ++mt) {
                    #pragma unroll
                    for (int r = 0; r < 4; ++r) {
                        float pv = __expf(sf[mt][nt][r] - me);
                        ts += pv;
                        pw[(nt * 16 + l15) * PSTR + mt * 16 + l4 * 4 + r] = pk1(pv);
                    }
                }
                ts += __shfl_xor(ts, 16, 64);
                ts += __shfl_xor(ts, 32, 64);
                lrow[nt] = lrow[nt] * alpha[nt] + ts;
            }
            // ---------- rescale O by alpha (column stats -> row layout) -----
            #pragma unroll
            for (int mt = 0; mt < 2; ++mt) {
                #pragma unroll
                for (int r = 0; r < 4; ++r) {
                    float ar = __shfl(alpha[mt], l4 * 4 + r, 64);
                    #pragma unroll
                    for (int nt = 0; nt < 8; ++nt) O[mt][nt][r] *= ar;
                }
            }
            // ---------- O += P · V ----------
            #pragma unroll
            for (int ks = 0; ks < 2; ++ks) {
                bf16x8 pa[2];
                #pragma unroll
                for (int mt = 0; mt < 2; ++mt)
                    pa[mt] = *reinterpret_cast<const bf16x8*>(
                        &pw[(mt * 16 + l15) * PSTR + ks * 32 + l4 * 8]);
                #pragma unroll
                for (int nt = 0; nt < 8; ++nt) {
                    bf16x8 vf = *reinterpret_cast<const bf16x8*>(
                        &lds_vt[(nt * 16 + l15) * VSTR + ks * 32 + l4 * 8]);
                    #pragma unroll
                    for (int mt = 0; mt < 2; ++mt)
                        O[mt][nt] = __builtin_amdgcn_mfma_f32_16x16x32_bf16(
                            pa[mt], vf, O[mt][nt], 0, 0, 0);
                }
            }
        }
        __syncthreads();
    }

    // ---------- epilogue: O / l, f32 out ----------
    #pragma unroll
    for (int mt = 0; mt < 2; ++mt) {
        float inv = 1.0f / lrow[mt];
        #pragma unroll
        for (int r = 0; r < 4; ++r) {
            float li = __shfl(inv, l4 * 4 + r, 64);
            int row = i0 + mt * 16 + l4 * 4 + r;
            float* orow = out + qbase + (size_t)row * HD;
            #pragma unroll
            for (int nt = 0; nt < 8; ++nt)
                orow[nt * 16 + l15] = O[mt][nt][r] * li;
        }
    }
}

extern "C" void kernel_launch(void* const* d_in, const int* in_sizes, int n_in,
                              void* d_out, int out_size, void* d_ws, size_t ws_size,
                              hipStream_t stream) {
    const float* q = (const float*)d_in[0];
    const float* k = (const float*)d_in[1];
    const float* v = (const float*)d_in[2];
    float* out     = (float*)d_out;

    hipLaunchKernelGGL(fa_mfma, dim3(BATCH * NH * (SEQ / 128)), dim3(256), 0, stream,
                       q, k, v, out);
}

// Round 6
// 130.396 us; speedup vs baseline: 15.3646x; 1.3918x over previous
//
#include <hip/hip_runtime.h>
#include <hip/hip_bf16.h>
#include <stdint.h>

#define SEQ 2048
#define HD  128
#define WIN 512
#define NH  16
#define NKV 4
#define BATCH 2

typedef __attribute__((ext_vector_type(8))) short bf16x8;
typedef __attribute__((ext_vector_type(4))) float f32x4;

// v_exp_f32: D = 2^S0 — avoids the glibc __exp2f macro collision
#define EXP2(x) __builtin_amdgcn_exp2f(x)

// LDS row strides in bf16 elements (all byte-strides multiples of 16B for b128)
#define KSTR 136   // K tile  [64 keys][128 dims]
#define VSTR 72    // V^T tile [128 dims][64 keys]
#define PSTR 72    // P tile per wave [32 q][64 keys]

__device__ __forceinline__ uint32_t pk2(float a, float b) {
    __hip_bfloat162 h = __float22bfloat162_rn(make_float2(a, b));
    return *reinterpret_cast<uint32_t*>(&h);
}
__device__ __forceinline__ uint16_t pk1(float a) {
    __hip_bfloat16 h = __float2bfloat16(a);
    return *reinterpret_cast<uint16_t*>(&h);
}

// 4 waves/block, 32 queries/wave, 128/block. S^T = K·Q^T so softmax stats are
// per-column (q = lane&15). Register-prefetch pipeline: tile kt+1's global
// loads are issued before tile kt's compute; V transposed in registers
// (8key x 4dim block/thread) -> b128 LDS writes.
__global__ __launch_bounds__(256, 2) void fa_mfma(
    const float* __restrict__ q,
    const float* __restrict__ k,
    const float* __restrict__ v,
    float* __restrict__ out)
{
    const int tid  = threadIdx.x;
    const int wave = tid >> 6;
    const int lane = tid & 63;
    const int l4   = lane >> 4;
    const int l15  = lane & 15;

    const int bh   = blockIdx.x >> 4;      // b*NH + h
    const int qblk = blockIdx.x & 15;
    const int q0   = qblk << 7;            // 128 queries per block
    const int hkv  = (bh & (NH - 1)) >> 2; // G = 4
    const int b    = bh >> 4;

    const int i0   = q0 + wave * 32;       // wave's first query row

    __shared__ __align__(16) uint16_t lds_k[64 * KSTR];
    __shared__ __align__(16) uint16_t lds_vt[HD * VSTR];
    __shared__ __align__(16) uint16_t lds_p[4 * 32 * PSTR];
    uint16_t* pw = &lds_p[wave * 32 * PSTR];

    // scale * log2(e): softmax computed in exp2 domain
    const float scale2 = 0.08838834764831845f * 1.4426950408889634f;

    const size_t qbase  = (size_t)bh * SEQ * HD;
    const size_t kvbase = (size_t)(b * NKV + hkv) * SEQ * HD;

    // ---- preload Q fragments (B-operand: B[k=dim][n=q]) ----
    union { bf16x8 f; uint32_t u[4]; } qf[2][4];
    #pragma unroll
    for (int nt = 0; nt < 2; ++nt) {
        const float* qr = q + qbase + (size_t)(i0 + nt * 16 + l15) * HD;
        #pragma unroll
        for (int ks = 0; ks < 4; ++ks) {
            const float4* g = reinterpret_cast<const float4*>(qr + ks * 32 + l4 * 8);
            float4 a = g[0], bq = g[1];
            qf[nt][ks].u[0] = pk2(a.x * scale2, a.y * scale2);
            qf[nt][ks].u[1] = pk2(a.z * scale2, a.w * scale2);
            qf[nt][ks].u[2] = pk2(bq.x * scale2, bq.y * scale2);
            qf[nt][ks].u[3] = pk2(bq.z * scale2, bq.w * scale2);
        }
    }

    f32x4 O[2][8];
    #pragma unroll
    for (int a1 = 0; a1 < 2; ++a1)
        #pragma unroll
        for (int a2 = 0; a2 < 8; ++a2) O[a1][a2] = (f32x4){0.f, 0.f, 0.f, 0.f};
    float mrow[2] = {-1e30f, -1e30f};
    float lrow[2] = {0.f, 0.f};

    const int kt_lo_blk = (q0 >= 512) ? ((q0 - 511) >> 6) : 0;
    const int kt_hi_blk = (q0 + 127) >> 6;
    const int lo_w = (i0 >= 512) ? ((i0 - 511) >> 6) : 0;
    const int hi_w = (i0 + 31) >> 6;

    // ---- prefetch registers ----
    const int vdg = tid & 31;   // dim group (4 dims)
    const int vkg = tid >> 5;   // key group (8 keys)
    float4 rKa[4], rKb[4], rV[8];

    auto prefetch = [&](int kt) {
        const float* kp = k + kvbase + (size_t)kt * 64 * HD;
        const float* vp = v + kvbase + (size_t)kt * 64 * HD;
        #pragma unroll
        for (int it = 0; it < 4; ++it) {
            int flat8 = tid + it * 256, key = flat8 >> 4, ch = flat8 & 15;
            const float4* g = reinterpret_cast<const float4*>(kp + key * HD + ch * 8);
            rKa[it] = g[0]; rKb[it] = g[1];
        }
        #pragma unroll
        for (int r = 0; r < 8; ++r)
            rV[r] = *reinterpret_cast<const float4*>(vp + (vkg * 8 + r) * HD + vdg * 4);
    };

    prefetch(kt_lo_blk);

    for (int kt = kt_lo_blk; kt <= kt_hi_blk; ++kt) {
        // ---------- pack prefetched K tile -> LDS (b128 writes) ----------
        #pragma unroll
        for (int it = 0; it < 4; ++it) {
            int flat8 = tid + it * 256, key = flat8 >> 4, ch = flat8 & 15;
            uint4 wv;
            wv.x = pk2(rKa[it].x, rKa[it].y);  wv.y = pk2(rKa[it].z, rKa[it].w);
            wv.z = pk2(rKb[it].x, rKb[it].y);  wv.w = pk2(rKb[it].z, rKb[it].w);
            *reinterpret_cast<uint4*>(&lds_k[key * KSTR + ch * 8]) = wv;
        }
        // ---------- pack prefetched V (register 8x4 transpose) -> LDS ------
        {
            const float* rvf = reinterpret_cast<const float*>(rV);
            #pragma unroll
            for (int i = 0; i < 4; ++i) {
                uint4 wv;
                wv.x = pk2(rvf[0 * 4 + i], rvf[1 * 4 + i]);
                wv.y = pk2(rvf[2 * 4 + i], rvf[3 * 4 + i]);
                wv.z = pk2(rvf[4 * 4 + i], rvf[5 * 4 + i]);
                wv.w = pk2(rvf[6 * 4 + i], rvf[7 * 4 + i]);
                *reinterpret_cast<uint4*>(&lds_vt[(vdg * 4 + i) * VSTR + vkg * 8]) = wv;
            }
        }
        __syncthreads();

        // ---------- issue next tile's global loads (overlap with compute) --
        if (kt < kt_hi_blk) prefetch(kt + 1);

        if (kt >= lo_w && kt <= hi_w) {
            // ---------- S^T = K · Q^T ----------
            f32x4 sf[4][2];
            #pragma unroll
            for (int mt = 0; mt < 4; ++mt) {
                #pragma unroll
                for (int nt = 0; nt < 2; ++nt) sf[mt][nt] = (f32x4){0.f, 0.f, 0.f, 0.f};
                #pragma unroll
                for (int ks = 0; ks < 4; ++ks) {
                    bf16x8 af = *reinterpret_cast<const bf16x8*>(
                        &lds_k[(mt * 16 + l15) * KSTR + ks * 32 + l4 * 8]);
                    #pragma unroll
                    for (int nt = 0; nt < 2; ++nt)
                        sf[mt][nt] = __builtin_amdgcn_mfma_f32_16x16x32_bf16(
                            af, qf[nt][ks].f, sf[mt][nt], 0, 0, 0);
                }
            }
            // ---------- mask (first/window and last/causal tiles only) ------
            const bool needmask = (kt == hi_w) || (kt == lo_w && i0 > 511);
            if (needmask) {
                #pragma unroll
                for (int mt = 0; mt < 4; ++mt) {
                    int jb = kt * 64 + mt * 16 + l4 * 4;
                    #pragma unroll
                    for (int nt = 0; nt < 2; ++nt) {
                        int iq = i0 + nt * 16 + l15;
                        #pragma unroll
                        for (int r = 0; r < 4; ++r) {
                            int j = jb + r;
                            if (!((j <= iq) && (iq - j < WIN))) sf[mt][nt][r] = -1e30f;
                        }
                    }
                }
            }
            // ---------- online softmax, exp2 domain (per-column stats) ------
            float alpha[2];
            #pragma unroll
            for (int nt = 0; nt < 2; ++nt) {
                float tm = -1e30f;
                #pragma unroll
                for (int mt = 0; mt < 4; ++mt)
                    #pragma unroll
                    for (int r = 0; r < 4; ++r) tm = fmaxf(tm, sf[mt][nt][r]);
                tm = fmaxf(tm, __shfl_xor(tm, 16, 64));
                tm = fmaxf(tm, __shfl_xor(tm, 32, 64));
                float mn = fmaxf(mrow[nt], tm);
                alpha[nt] = EXP2(mrow[nt] - mn);
                mrow[nt] = mn;
                float me = fmaxf(mn, -1e20f);   // fully-masked rows -> p = 0
                float ts = 0.f;
                #pragma unroll
                for (int mt = 0; mt < 4; ++mt) {
                    #pragma unroll
                    for (int r = 0; r < 4; ++r) {
                        float pv = EXP2(sf[mt][nt][r] - me);
                        ts += pv;
                        pw[(nt * 16 + l15) * PSTR + mt * 16 + l4 * 4 + r] = pk1(pv);
                    }
                }
                ts += __shfl_xor(ts, 16, 64);
                ts += __shfl_xor(ts, 32, 64);
                lrow[nt] = lrow[nt] * alpha[nt] + ts;
            }
            // ---------- rescale O by alpha (column stats -> row layout) -----
            #pragma unroll
            for (int mt = 0; mt < 2; ++mt) {
                #pragma unroll
                for (int r = 0; r < 4; ++r) {
                    float ar = __shfl(alpha[mt], l4 * 4 + r, 64);
                    #pragma unroll
                    for (int nt = 0; nt < 8; ++nt) O[mt][nt][r] *= ar;
                }
            }
            // ---------- O += P · V ----------
            #pragma unroll
            for (int ks = 0; ks < 2; ++ks) {
                bf16x8 pa[2];
                #pragma unroll
                for (int mt = 0; mt < 2; ++mt)
                    pa[mt] = *reinterpret_cast<const bf16x8*>(
                        &pw[(mt * 16 + l15) * PSTR + ks * 32 + l4 * 8]);
                #pragma unroll
                for (int nt = 0; nt < 8; ++nt) {
                    bf16x8 vf = *reinterpret_cast<const bf16x8*>(
                        &lds_vt[(nt * 16 + l15) * VSTR + ks * 32 + l4 * 8]);
                    #pragma unroll
                    for (int mt = 0; mt < 2; ++mt)
                        O[mt][nt] = __builtin_amdgcn_mfma_f32_16x16x32_bf16(
                            pa[mt], vf, O[mt][nt], 0, 0, 0);
                }
            }
        }
        __syncthreads();
    }

    // ---------- epilogue: O / l, f32 out ----------
    #pragma unroll
    for (int mt = 0; mt < 2; ++mt) {
        float inv = 1.0f / lrow[mt];
        #pragma unroll
        for (int r = 0; r < 4; ++r) {
            float li = __shfl(inv, l4 * 4 + r, 64);
            int row = i0 + mt * 16 + l4 * 4 + r;
            float* orow = out + qbase + (size_t)row * HD;
            #pragma unroll
            for (int nt = 0; nt < 8; ++nt)
                orow[nt * 16 + l15] = O[mt][nt][r] * li;
        }
    }
}

extern "C" void kernel_launch(void* const* d_in, const int* in_sizes, int n_in,
                              void* d_out, int out_size, void* d_ws, size_t ws_size,
                              hipStream_t stream) {
    const float* q = (const float*)d_in[0];
    const float* k = (const float*)d_in[1];
    const float* v = (const float*)d_in[2];
    float* out     = (float*)d_out;

    hipLaunchKernelGGL(fa_mfma, dim3(BATCH * NH * (SEQ / 128)), dim3(256), 0, stream,
                       q, k, v, out);
}